// Round 5
// baseline (165.011 us; speedup 1.0000x reference)
//
#include <hip/hip_runtime.h>
#include <hip/hip_bf16.h>
#include <stdint.h>

#define NQ 8192
#define NT 8192
#define DIM 512
#define BK 64
#define NKT (DIM / BK)      // 8 K-tiles (segments)
#define BM 256
#define BN 256

typedef __hip_bfloat16 bf16;
using bf16x8  = __attribute__((ext_vector_type(8))) short;
using f32x16  = __attribute__((ext_vector_type(16))) float;
using short8v = __attribute__((ext_vector_type(8))) short;

typedef __attribute__((address_space(1))) void* gas1_t;
typedef __attribute__((address_space(3))) void* las3_t;

// ---------------- zero the output (harness poisons with 0xAA) ---------------
__global__ void zero_out_k(float* __restrict__ out) {
    out[blockIdx.x * 256 + threadIdx.x] = 0.0f;
}

// ---------------- prepass: fp32 -> bf16 + row norms -------------------------
__global__ void prep_k(const float* __restrict__ X, const float* __restrict__ T,
                       bf16* __restrict__ Xb, bf16* __restrict__ Tb,
                       float* __restrict__ x2, float* __restrict__ y2) {
    const int w    = threadIdx.x >> 6;
    const int lane = threadIdx.x & 63;
    const int wid  = blockIdx.x * 4 + w;
#pragma unroll
    for (int rr = 0; rr < 2; ++rr) {
        const int row = wid * 2 + rr;
        const float* src; bf16* dst; float* nrm; int r;
        if (row < NQ) { r = row;      src = X + (size_t)r * DIM; dst = Xb + (size_t)r * DIM; nrm = x2; }
        else          { r = row - NQ; src = T + (size_t)r * DIM; dst = Tb + (size_t)r * DIM; nrm = y2; }
        const float4 v0 = reinterpret_cast<const float4*>(src)[lane * 2];
        const float4 v1 = reinterpret_cast<const float4*>(src)[lane * 2 + 1];
        float s = v0.x*v0.x + v0.y*v0.y + v0.z*v0.z + v0.w*v0.w
                + v1.x*v1.x + v1.y*v1.y + v1.z*v1.z + v1.w*v1.w;
        short8v pk;
        pk[0] = (short)__bfloat16_as_ushort(__float2bfloat16(v0.x));
        pk[1] = (short)__bfloat16_as_ushort(__float2bfloat16(v0.y));
        pk[2] = (short)__bfloat16_as_ushort(__float2bfloat16(v0.z));
        pk[3] = (short)__bfloat16_as_ushort(__float2bfloat16(v0.w));
        pk[4] = (short)__bfloat16_as_ushort(__float2bfloat16(v1.x));
        pk[5] = (short)__bfloat16_as_ushort(__float2bfloat16(v1.y));
        pk[6] = (short)__bfloat16_as_ushort(__float2bfloat16(v1.z));
        pk[7] = (short)__bfloat16_as_ushort(__float2bfloat16(v1.w));
        reinterpret_cast<short8v*>(dst)[lane] = pk;
#pragma unroll
        for (int off = 32; off; off >>= 1) s += __shfl_xor(s, off, 64);
        if (lane == 0) nrm[r] = s;
    }
}

// ---- stage one half-tile (128 rows x 64 k) for K-tile kt into dstHalf ------
// LDS image swizzle: logical (row R, 16B-chunk c) at phys chunk c ^ (R&7).
// gload_lds writes linearly (wave base + lane*16): lane -> (row=R0+(lane>>3),
// phys=lane&7), so the lane fetches logical chunk (lane&7)^((lane>>3)&7).
__device__ __forceinline__ void stage_half(
    const bf16* __restrict__ src, int rowBase, int kt, bf16* dstHalf, int w, int lane) {
    const int k0 = kt * BK;
    const int rl = lane >> 3;
    const int cl = (lane & 7) ^ rl;
#pragma unroll
    for (int j = 0; j < 2; ++j) {
        const int R0 = w * 16 + j * 8;      // wave-uniform
        const bf16* g = src + (size_t)(rowBase + R0 + rl) * DIM + k0 + cl * 8;
        __builtin_amdgcn_global_load_lds((gas1_t)g, (las3_t)(dstHalf + R0 * BK), 16, 0, 0);
    }
}

// ---- swizzled fragment read: row-local [256][64] buf, ks k-slice, kg=lane>>5
__device__ __forceinline__ bf16x8 lds_frag(const bf16* buf, int row, int ks, int kg) {
    const int cl = ks * 2 + kg;
    return *reinterpret_cast<const bf16x8*>(buf + row * BK + ((cl ^ (row & 7)) << 3));
}

#define MFMA32(A, B, C) __builtin_amdgcn_mfma_f32_32x32x16_bf16(A, B, C, 0, 0, 0)

// ---- one segment: compute K-tile s from bufC, stage per the ledger ---------
// Quadrants: Q1(mh0,nh0) Q2(mh0,nh1) Q3(mh1,nh1) Q4(mh1,nh0).
// Stages: Ph1 (s+1)A1->bufN, Ph2 (s+1)B0->bufN, Ph3 (s+2)A0->bufC,
//         Ph4 (s+2)B1->bufC.  End-of-segment: vmcnt(VMC) + barrier.
template<bool ST12, bool ST34, int VMC>
__device__ __forceinline__ void segment(
    const bf16* __restrict__ Tb, const bf16* __restrict__ Xb,
    int tBlk, int qBlk, bf16* bufC, bf16* bufN, int s,
    int wm, int wn, int w, int lane, f32x16 (&acc)[4][2]) {

    const bf16* cA = bufC;
    const bf16* cB = bufC + 16384;
    bf16* nA = bufN;
    bf16* nB = bufN + 16384;
    const int l31 = lane & 31;
    const int kg  = lane >> 5;

    bf16x8 aF[2][4], b0[4], b1[4];

    // ---------- Phase 1: Q1 ----------
#pragma unroll
    for (int mi = 0; mi < 2; ++mi) {
        const int row = wm * 64 + mi * 32 + l31;          // m-half0 (A rows 0..127)
#pragma unroll
        for (int ks = 0; ks < 4; ++ks) aF[mi][ks] = lds_frag(cA, row, ks, kg);
    }
    {
        const int row = wn * 32 + l31;                    // n-half0 (B rows 0..127)
#pragma unroll
        for (int ks = 0; ks < 4; ++ks) b0[ks] = lds_frag(cB, row, ks, kg);
    }
    if (ST12) stage_half(Tb, tBlk + 128, s + 1, nA + 8192, w, lane);
    __builtin_amdgcn_s_barrier();
    asm volatile("s_waitcnt lgkmcnt(0)" ::: "memory");
    __builtin_amdgcn_sched_barrier(0);
    __builtin_amdgcn_s_setprio(1);
#pragma unroll
    for (int ks = 0; ks < 4; ++ks) {
        acc[0][0] = MFMA32(aF[0][ks], b0[ks], acc[0][0]);
        acc[1][0] = MFMA32(aF[1][ks], b0[ks], acc[1][0]);
    }
    __builtin_amdgcn_s_setprio(0);
    __builtin_amdgcn_s_barrier();

    // ---------- Phase 2: Q2 ----------
    {
        const int row = 128 + wn * 32 + l31;              // n-half1
#pragma unroll
        for (int ks = 0; ks < 4; ++ks) b1[ks] = lds_frag(cB, row, ks, kg);
    }
    if (ST12) stage_half(Xb, qBlk + 0, s + 1, nB + 0, w, lane);
    __builtin_amdgcn_s_barrier();
    asm volatile("s_waitcnt lgkmcnt(0)" ::: "memory");
    __builtin_amdgcn_sched_barrier(0);
    __builtin_amdgcn_s_setprio(1);
#pragma unroll
    for (int ks = 0; ks < 4; ++ks) {
        acc[0][1] = MFMA32(aF[0][ks], b1[ks], acc[0][1]);
        acc[1][1] = MFMA32(aF[1][ks], b1[ks], acc[1][1]);
    }
    __builtin_amdgcn_s_setprio(0);
    __builtin_amdgcn_s_barrier();

    // ---------- Phase 3: Q3 ----------
#pragma unroll
    for (int mi = 0; mi < 2; ++mi) {
        const int row = 128 + wm * 64 + mi * 32 + l31;    // m-half1
#pragma unroll
        for (int ks = 0; ks < 4; ++ks) aF[mi][ks] = lds_frag(cA, row, ks, kg);
    }
    if (ST34) stage_half(Tb, tBlk + 0, s + 2, bufC + 0, w, lane);
    __builtin_amdgcn_s_barrier();
    asm volatile("s_waitcnt lgkmcnt(0)" ::: "memory");
    __builtin_amdgcn_sched_barrier(0);
    __builtin_amdgcn_s_setprio(1);
#pragma unroll
    for (int ks = 0; ks < 4; ++ks) {
        acc[2][1] = MFMA32(aF[0][ks], b1[ks], acc[2][1]);
        acc[3][1] = MFMA32(aF[1][ks], b1[ks], acc[3][1]);
    }
    __builtin_amdgcn_s_setprio(0);
    __builtin_amdgcn_s_barrier();

    // ---------- Phase 4: Q4 (no new ds_reads; b0 still in regs) ----------
    if (ST34) stage_half(Xb, qBlk + 128, s + 2, bufC + 16384 + 8192, w, lane);
    __builtin_amdgcn_s_setprio(1);
#pragma unroll
    for (int ks = 0; ks < 4; ++ks) {
        acc[2][0] = MFMA32(aF[0][ks], b0[ks], acc[2][0]);
        acc[3][0] = MFMA32(aF[1][ks], b0[ks], acc[3][0]);
    }
    __builtin_amdgcn_s_setprio(0);
    if (VMC == 4)      asm volatile("s_waitcnt vmcnt(4)" ::: "memory");
    else if (VMC == 0) asm volatile("s_waitcnt vmcnt(0)" ::: "memory");
    __builtin_amdgcn_s_barrier();
    __builtin_amdgcn_sched_barrier(0);
}

// ---------------- main: 256x256, 8 waves, 8-phase-style schedule ------------
__global__ __launch_bounds__(512, 2) void krr_mfma_k(
    const bf16* __restrict__ Tb, const bf16* __restrict__ Xb,
    const float* __restrict__ x2, const float* __restrict__ y2,
    const float* __restrict__ coef, float* __restrict__ out) {

    __shared__ bf16 lds[2 * 32768];           // 128 KB: 2 bufs x (A 32K + B 32K)

    const int tid  = threadIdx.x;
    const int w    = tid >> 6;
    const int lane = tid & 63;
    const int wm   = w >> 2;                  // 0/1
    const int wn   = w & 3;                   // 0..3

    const int qBlk = blockIdx.x * BN;
    const int tBlk = blockIdx.y * BM;

    bf16* b0 = lds;
    bf16* b1 = lds + 32768;

    f32x16 acc[4][2];
#pragma unroll
    for (int mi = 0; mi < 4; ++mi)
#pragma unroll
        for (int ni = 0; ni < 2; ++ni)
#pragma unroll
            for (int r = 0; r < 16; ++r) acc[mi][ni][r] = 0.f;

    // prologue: tile0 fully + tile1 A0,B1  (oldest 8 = tile 0 -> vmcnt(4))
    stage_half(Tb, tBlk + 0,   0, b0 + 0,             w, lane);   // (0)A0
    stage_half(Xb, qBlk + 128, 0, b0 + 16384 + 8192,  w, lane);   // (0)B1
    stage_half(Tb, tBlk + 128, 0, b0 + 8192,          w, lane);   // (0)A1
    stage_half(Xb, qBlk + 0,   0, b0 + 16384,         w, lane);   // (0)B0
    stage_half(Tb, tBlk + 0,   1, b1 + 0,             w, lane);   // (1)A0
    stage_half(Xb, qBlk + 128, 1, b1 + 16384 + 8192,  w, lane);   // (1)B1
    asm volatile("s_waitcnt vmcnt(4)" ::: "memory");
    __builtin_amdgcn_s_barrier();
    __builtin_amdgcn_sched_barrier(0);

#pragma unroll 1
    for (int it = 0; it < 3; ++it) {          // segments 0..5
        segment<true, true, 4>(Tb, Xb, tBlk, qBlk, b0, b1, 2 * it,     wm, wn, w, lane, acc);
        segment<true, true, 4>(Tb, Xb, tBlk, qBlk, b1, b0, 2 * it + 1, wm, wn, w, lane, acc);
    }
    segment<true,  false, 0>(Tb, Xb, tBlk, qBlk, b0, b1, 6, wm, wn, w, lane, acc);
    segment<false, false, -1>(Tb, Xb, tBlk, qBlk, b1, b0, 7, wm, wn, w, lane, acc);

    // ---- epilogue: s += exp(-(x2+y2-2*dot)) * coef, reduce over t ----------
    // C/D 32x32: col = lane&31 (q), row = (r&3) + 8*(r>>2) + 4*(lane>>5) (t)
    const int l31 = lane & 31;
    const int q0  = qBlk + wn * 32 + l31;
    const int q1  = q0 + 128;
    const float x2q0 = x2[q0];
    const float x2q1 = x2[q1];
    float s0 = 0.f, s1 = 0.f;
#pragma unroll
    for (int mi = 0; mi < 4; ++mi) {
        const int tb = tBlk + (mi >> 1) * 128 + wm * 64 + (mi & 1) * 32 + 4 * (lane >> 5);
        float y2v[16], cfv[16];
#pragma unroll
        for (int r = 0; r < 16; ++r) {
            const int t = tb + (r & 3) + 8 * (r >> 2);
            y2v[r] = y2[t];
            cfv[r] = coef[t];
        }
#pragma unroll
        for (int r = 0; r < 16; ++r) {
            s0 += __expf(-fmaxf(x2q0 + y2v[r] - 2.0f * acc[mi][0][r], 0.f)) * cfv[r];
            s1 += __expf(-fmaxf(x2q1 + y2v[r] - 2.0f * acc[mi][1][r], 0.f)) * cfv[r];
        }
    }
    s0 += __shfl_xor(s0, 32, 64);
    s1 += __shfl_xor(s1, 32, 64);
    if (lane < 32) {
        atomicAdd(&out[q0], s0);
        atomicAdd(&out[q1], s1);
    }
}

// ---------------- fallback: plain fp32, no workspace ------------------------
__global__ void krr_naive_k(const float* __restrict__ X, const float* __restrict__ T,
                            const float* __restrict__ coef, float* __restrict__ out) {
    __shared__ float xq[DIM];
    const int q = blockIdx.x;
    for (int i = threadIdx.x; i < DIM; i += 256) xq[i] = X[(size_t)q * DIM + i];
    __syncthreads();
    float s2 = 0.f;
    for (int i = 0; i < DIM; ++i) s2 += xq[i] * xq[i];
    float acc = 0.f;
    for (int t = threadIdx.x; t < NT; t += 256) {
        const float* ty = T + (size_t)t * DIM;
        float dot = 0.f, yy = 0.f;
        for (int i = 0; i < DIM; ++i) { float yv = ty[i]; dot += xq[i] * yv; yy += yv * yv; }
        float sq = fmaxf(s2 + yy - 2.0f * dot, 0.f);
        acc += __expf(-sq) * coef[t];
    }
#pragma unroll
    for (int off = 32; off > 0; off >>= 1) acc += __shfl_down(acc, off, 64);
    __shared__ float red[4];
    if ((threadIdx.x & 63) == 0) red[threadIdx.x >> 6] = acc;
    __syncthreads();
    if (threadIdx.x == 0) out[q] = red[0] + red[1] + red[2] + red[3];
}

extern "C" void kernel_launch(void* const* d_in, const int* in_sizes, int n_in,
                              void* d_out, int out_size, void* d_ws, size_t ws_size,
                              hipStream_t stream) {
    const float* X    = (const float*)d_in[0];
    const float* T    = (const float*)d_in[1];
    const float* coef = (const float*)d_in[2];
    float* out = (float*)d_out;

    zero_out_k<<<NQ / 256, 256, 0, stream>>>(out);

    const size_t need = (size_t)(NQ + NT) * DIM * sizeof(bf16) + (size_t)(NQ + NT) * sizeof(float);
    if (ws_size >= need) {
        bf16* Xb  = (bf16*)d_ws;
        bf16* Tb  = Xb + (size_t)NQ * DIM;
        float* x2 = (float*)(Tb + (size_t)NT * DIM);
        float* y2 = x2 + NQ;
        prep_k<<<2048, 256, 0, stream>>>(X, T, Xb, Tb, x2, y2);
        dim3 grid(NQ / BN, NT / BM);
        krr_mfma_k<<<grid, 512, 0, stream>>>(Tb, Xb, x2, y2, coef, out);
    } else {
        krr_naive_k<<<NQ, 256, 0, stream>>>(X, T, coef, out);
    }
}

// Round 11
// 155.216 us; speedup vs baseline: 1.0631x; 1.0631x over previous
//
#include <hip/hip_runtime.h>
#include <hip/hip_bf16.h>
#include <stdint.h>

#define NQ 8192
#define NT 8192
#define DIM 512
#define BK 32
#define NKT (DIM / BK)            // 16 K-tiles
#define BM 256
#define BN 256
#define AELEMS (BM * BK)          // 8192 elems (16 KB) per A tile
#define BUF_ELEMS ((BM + BN) * BK) // 16384 elems (32 KB) per buffer

typedef __hip_bfloat16 bf16;
using bf16x8  = __attribute__((ext_vector_type(8))) short;
using f32x4   = __attribute__((ext_vector_type(4))) float;
using short8v = __attribute__((ext_vector_type(8))) short;

typedef __attribute__((address_space(1))) void* gas1_t;
typedef __attribute__((address_space(3))) void* las3_t;

// ---------------- zero the output (harness poisons with 0xAA) ---------------
__global__ void zero_out_k(float* __restrict__ out) {
    out[blockIdx.x * 256 + threadIdx.x] = 0.0f;
}

// ---------------- prepass: fp32 -> bf16 + row norms -------------------------
__global__ void prep_k(const float* __restrict__ X, const float* __restrict__ T,
                       bf16* __restrict__ Xb, bf16* __restrict__ Tb,
                       float* __restrict__ x2, float* __restrict__ y2) {
    const int w    = threadIdx.x >> 6;
    const int lane = threadIdx.x & 63;
    const int wid  = blockIdx.x * 4 + w;
#pragma unroll
    for (int rr = 0; rr < 2; ++rr) {
        const int row = wid * 2 + rr;
        const float* src; bf16* dst; float* nrm; int r;
        if (row < NQ) { r = row;      src = X + (size_t)r * DIM; dst = Xb + (size_t)r * DIM; nrm = x2; }
        else          { r = row - NQ; src = T + (size_t)r * DIM; dst = Tb + (size_t)r * DIM; nrm = y2; }
        const float4 v0 = reinterpret_cast<const float4*>(src)[lane * 2];
        const float4 v1 = reinterpret_cast<const float4*>(src)[lane * 2 + 1];
        float s = v0.x*v0.x + v0.y*v0.y + v0.z*v0.z + v0.w*v0.w
                + v1.x*v1.x + v1.y*v1.y + v1.z*v1.z + v1.w*v1.w;
        short8v pk;
        pk[0] = (short)__bfloat16_as_ushort(__float2bfloat16(v0.x));
        pk[1] = (short)__bfloat16_as_ushort(__float2bfloat16(v0.y));
        pk[2] = (short)__bfloat16_as_ushort(__float2bfloat16(v0.z));
        pk[3] = (short)__bfloat16_as_ushort(__float2bfloat16(v0.w));
        pk[4] = (short)__bfloat16_as_ushort(__float2bfloat16(v1.x));
        pk[5] = (short)__bfloat16_as_ushort(__float2bfloat16(v1.y));
        pk[6] = (short)__bfloat16_as_ushort(__float2bfloat16(v1.z));
        pk[7] = (short)__bfloat16_as_ushort(__float2bfloat16(v1.w));
        reinterpret_cast<short8v*>(dst)[lane] = pk;
#pragma unroll
        for (int off = 32; off; off >>= 1) s += __shfl_xor(s, off, 64);
        if (lane == 0) nrm[r] = s;
    }
}

// ---- stage one operand (256 rows x 32 k) of tile kt: 2 gloads per wave -----
// Swizzle (0-conflict, measured r3): logical (row R, 16B-chunk c) lives at
// physical chunk c ^ (((R%16)>>1)&3); gload_lds writes linearly, so the
// per-lane GLOBAL source is pre-swizzled (both-sides rule).
__device__ __forceinline__ void stage_rows(
    const bf16* __restrict__ src, int rowBase, int kt, bf16* dst, int w, int lane) {
    const int k0 = kt * BK;
    const int rl = lane >> 2;                  // 0..15: row in 16-row group
    const int c  = (lane & 3) ^ ((rl >> 1) & 3);
#pragma unroll
    for (int j = 0; j < 2; ++j) {
        const int R0 = w * 32 + j * 16;        // wave-uniform
        const bf16* g = src + (size_t)(rowBase + R0 + rl) * DIM + k0 + c * 8;
        __builtin_amdgcn_global_load_lds((gas1_t)g, (las3_t)(dst + R0 * BK), 16, 0, 0);
    }
}

// ---- swizzled fragment read: fr = lane&15 (row), fc = lane>>4 (k-chunk) ----
__device__ __forceinline__ bf16x8 frag(const bf16* base, int row, int fc) {
    return *reinterpret_cast<const bf16x8*>(
        base + row * BK + ((fc ^ ((row >> 1) & 3)) << 3));
}

#define MFMA16(A, B, C) __builtin_amdgcn_mfma_f32_16x16x32_bf16(A, B, C, 0, 0, 0)

// ---- one K-tile = 2 phases (m201 geometry) ---------------------------------
// Phase A: 8 ds_read (a0..3 + b0..3) | stage A(tS) | bar | lgkm0 | 16 MFMA | bar
// Phase B: 4 ds_read (a4..7, b reused) | stage B(tS) | bar | lgkm0 | 16 MFMA
// End: vmcnt(VMC) + bar (counted: tile t+1's 4 loads are the oldest 4).
template<bool ST, int VMC>
__device__ __forceinline__ void ktile(
    const bf16* __restrict__ Tb, const bf16* __restrict__ Xb,
    int tBlk, int qBlk, int tS, const bf16* bufC, bf16* bufS,
    int wm, int wn, int w, int lane, f32x4 (&acc)[8][4]) {

    const bf16* cA = bufC;
    const bf16* cB = bufC + AELEMS;
    const int fr = lane & 15;
    const int fc = lane >> 4;

    bf16x8 a[4], b[4];

    // ---------- phase A ----------
#pragma unroll
    for (int m = 0; m < 4; ++m) a[m] = frag(cA, wm * 128 + m * 16 + fr, fc);
#pragma unroll
    for (int n = 0; n < 4; ++n) b[n] = frag(cB, wn * 64 + n * 16 + fr, fc);
    if (ST) stage_rows(Tb, tBlk, tS, bufS, w, lane);
    __builtin_amdgcn_s_barrier();
    asm volatile("s_waitcnt lgkmcnt(0)" ::: "memory");
    __builtin_amdgcn_sched_barrier(0);
    __builtin_amdgcn_s_setprio(1);
#pragma unroll
    for (int m = 0; m < 4; ++m)
#pragma unroll
        for (int n = 0; n < 4; ++n)
            acc[m][n] = MFMA16(a[m], b[n], acc[m][n]);
    __builtin_amdgcn_s_setprio(0);
    __builtin_amdgcn_s_barrier();

    // ---------- phase B ----------
#pragma unroll
    for (int m = 0; m < 4; ++m) a[m] = frag(cA, wm * 128 + (m + 4) * 16 + fr, fc);
    if (ST) stage_rows(Xb, qBlk, tS, bufS + AELEMS, w, lane);
    __builtin_amdgcn_s_barrier();
    asm volatile("s_waitcnt lgkmcnt(0)" ::: "memory");
    __builtin_amdgcn_sched_barrier(0);
    __builtin_amdgcn_s_setprio(1);
#pragma unroll
    for (int m = 0; m < 4; ++m)
#pragma unroll
        for (int n = 0; n < 4; ++n)
            acc[m + 4][n] = MFMA16(a[m], b[n], acc[m + 4][n]);
    __builtin_amdgcn_s_setprio(0);
    if (VMC == 4)      asm volatile("s_waitcnt vmcnt(4)" ::: "memory");
    else if (VMC == 0) asm volatile("s_waitcnt vmcnt(0)" ::: "memory");
    __builtin_amdgcn_s_barrier();
    __builtin_amdgcn_sched_barrier(0);
}

// ---------------- main: 256x256, 8 waves (2x4), per-wave 128x64 -------------
__global__ __launch_bounds__(512, 2) void krr_mfma_k(
    const bf16* __restrict__ Tb, const bf16* __restrict__ Xb,
    const float* __restrict__ x2, const float* __restrict__ y2,
    const float* __restrict__ coef, float* __restrict__ out) {

    __shared__ bf16 lds[3 * BUF_ELEMS];       // 96 KB: 3 x (A 16K + B 16K)

    const int tid  = threadIdx.x;
    const int w    = tid >> 6;
    const int lane = tid & 63;
    const int wm   = w >> 2;                  // 0/1  (t half: 128 rows)
    const int wn   = w & 3;                   // 0..3 (q quarter: 64 rows)

    const int qBlk = blockIdx.x * BN;
    const int tBlk = blockIdx.y * BM;

    f32x4 acc[8][4];
    const f32x4 z4 = {0.f, 0.f, 0.f, 0.f};
#pragma unroll
    for (int m = 0; m < 8; ++m)
#pragma unroll
        for (int n = 0; n < 4; ++n) acc[m][n] = z4;

    // prologue: tiles 0,1 (A then B each -> oldest 4 = tile 0 -> vmcnt(4))
    stage_rows(Tb, tBlk, 0, lds, w, lane);
    stage_rows(Xb, qBlk, 0, lds + AELEMS, w, lane);
    stage_rows(Tb, tBlk, 1, lds + BUF_ELEMS, w, lane);
    stage_rows(Xb, qBlk, 1, lds + BUF_ELEMS + AELEMS, w, lane);
    asm volatile("s_waitcnt vmcnt(4)" ::: "memory");
    __builtin_amdgcn_s_barrier();
    __builtin_amdgcn_sched_barrier(0);

    int bc = 0;
#pragma unroll 1
    for (int t = 0; t < NKT - 2; ++t) {       // 14 iters, stage t+2
        const int bs = (bc == 0) ? 2 : bc - 1; // (bc+2)%3
        ktile<true, 4>(Tb, Xb, tBlk, qBlk, t + 2,
                       lds + bc * BUF_ELEMS, lds + bs * BUF_ELEMS, wm, wn, w, lane, acc);
        bc = (bc == 2) ? 0 : bc + 1;
    }
    ktile<false, 0>(Tb, Xb, tBlk, qBlk, 0,
                    lds + bc * BUF_ELEMS, lds, wm, wn, w, lane, acc);   // t=14
    bc = (bc == 2) ? 0 : bc + 1;
    ktile<false, -1>(Tb, Xb, tBlk, qBlk, 0,
                     lds + bc * BUF_ELEMS, lds, wm, wn, w, lane, acc);  // t=15

    // ---- epilogue: s += exp(-(x2+y2-2*dot)) * coef, reduce over t ----------
    // C/D 16x16 (m89): col = lane&15 (q), row = (lane>>4)*4 + reg (t)
    float s[4], x2q[4];
#pragma unroll
    for (int n = 0; n < 4; ++n) {
        s[n]   = 0.f;
        x2q[n] = x2[qBlk + wn * 64 + n * 16 + (lane & 15)];
    }
#pragma unroll
    for (int m = 0; m < 8; ++m) {
        const int tb = tBlk + wm * 128 + m * 16 + ((lane >> 4) << 2);
        float y2v[4], cfv[4];
#pragma unroll
        for (int r = 0; r < 4; ++r) { y2v[r] = y2[tb + r]; cfv[r] = coef[tb + r]; }
#pragma unroll
        for (int n = 0; n < 4; ++n)
#pragma unroll
            for (int r = 0; r < 4; ++r) {
                const float d  = acc[m][n][r];
                const float sq = fmaxf(x2q[n] + y2v[r] - 2.0f * d, 0.f);
                s[n] += __expf(-sq) * cfv[r];
            }
    }
#pragma unroll
    for (int n = 0; n < 4; ++n) {
        float v = s[n];
        v += __shfl_xor(v, 16, 64);
        v += __shfl_xor(v, 32, 64);
        if (lane < 16) atomicAdd(&out[qBlk + wn * 64 + n * 16 + lane], v);
    }
}

// ---------------- fallback: plain fp32, no workspace ------------------------
__global__ void krr_naive_k(const float* __restrict__ X, const float* __restrict__ T,
                            const float* __restrict__ coef, float* __restrict__ out) {
    __shared__ float xq[DIM];
    const int q = blockIdx.x;
    for (int i = threadIdx.x; i < DIM; i += 256) xq[i] = X[(size_t)q * DIM + i];
    __syncthreads();
    float s2 = 0.f;
    for (int i = 0; i < DIM; ++i) s2 += xq[i] * xq[i];
    float acc = 0.f;
    for (int t = threadIdx.x; t < NT; t += 256) {
        const float* ty = T + (size_t)t * DIM;
        float dot = 0.f, yy = 0.f;
        for (int i = 0; i < DIM; ++i) { float yv = ty[i]; dot += xq[i] * yv; yy += yv * yv; }
        float sq = fmaxf(s2 + yy - 2.0f * dot, 0.f);
        acc += __expf(-sq) * coef[t];
    }
#pragma unroll
    for (int off = 32; off > 0; off >>= 1) acc += __shfl_down(acc, off, 64);
    __shared__ float red[4];
    if ((threadIdx.x & 63) == 0) red[threadIdx.x >> 6] = acc;
    __syncthreads();
    if (threadIdx.x == 0) out[q] = red[0] + red[1] + red[2] + red[3];
}

extern "C" void kernel_launch(void* const* d_in, const int* in_sizes, int n_in,
                              void* d_out, int out_size, void* d_ws, size_t ws_size,
                              hipStream_t stream) {
    const float* X    = (const float*)d_in[0];
    const float* T    = (const float*)d_in[1];
    const float* coef = (const float*)d_in[2];
    float* out = (float*)d_out;

    zero_out_k<<<NQ / 256, 256, 0, stream>>>(out);

    const size_t need = (size_t)(NQ + NT) * DIM * sizeof(bf16) + (size_t)(NQ + NT) * sizeof(float);
    if (ws_size >= need) {
        bf16* Xb  = (bf16*)d_ws;
        bf16* Tb  = Xb + (size_t)NQ * DIM;
        float* x2 = (float*)(Tb + (size_t)NT * DIM);
        float* y2 = x2 + NQ;
        prep_k<<<2048, 256, 0, stream>>>(X, T, Xb, Tb, x2, y2);
        dim3 grid(NQ / BN, NT / BM);
        krr_mfma_k<<<grid, 512, 0, stream>>>(Tb, Xb, x2, y2, coef, out);
    } else {
        krr_naive_k<<<NQ, 256, 0, stream>>>(X, T, coef, out);
    }
}

// Round 13
// 146.544 us; speedup vs baseline: 1.1260x; 1.0592x over previous
//
#include <hip/hip_runtime.h>
#include <hip/hip_bf16.h>
#include <stdint.h>

#define NQ 8192
#define NT 8192
#define DIM 512
#define BK 64
#define NKT (DIM / BK)             // 8 K-tiles
#define BM 256
#define BN 256
#define AELEMS (BM * BK)           // 16384 elems (32 KB) per operand tile
#define BUF_ELEMS ((BM + BN) * BK) // 32768 elems (64 KB) per buffer

typedef __hip_bfloat16 bf16;
using bf16x8  = __attribute__((ext_vector_type(8))) short;
using f32x4   = __attribute__((ext_vector_type(4))) float;
using short8v = __attribute__((ext_vector_type(8))) short;

typedef __attribute__((address_space(1))) void* gas1_t;
typedef __attribute__((address_space(3))) void* las3_t;

// ---------------- zero the output (harness poisons with 0xAA) ---------------
__global__ void zero_out_k(float* __restrict__ out) {
    out[blockIdx.x * 256 + threadIdx.x] = 0.0f;
}

// ---------------- prepass: fp32 -> bf16 + row norms -------------------------
__global__ void prep_k(const float* __restrict__ X, const float* __restrict__ T,
                       bf16* __restrict__ Xb, bf16* __restrict__ Tb,
                       float* __restrict__ x2, float* __restrict__ y2) {
    const int w    = threadIdx.x >> 6;
    const int lane = threadIdx.x & 63;
    const int wid  = blockIdx.x * 4 + w;
#pragma unroll
    for (int rr = 0; rr < 2; ++rr) {
        const int row = wid * 2 + rr;
        const float* src; bf16* dst; float* nrm; int r;
        if (row < NQ) { r = row;      src = X + (size_t)r * DIM; dst = Xb + (size_t)r * DIM; nrm = x2; }
        else          { r = row - NQ; src = T + (size_t)r * DIM; dst = Tb + (size_t)r * DIM; nrm = y2; }
        const float4 v0 = reinterpret_cast<const float4*>(src)[lane * 2];
        const float4 v1 = reinterpret_cast<const float4*>(src)[lane * 2 + 1];
        float s = v0.x*v0.x + v0.y*v0.y + v0.z*v0.z + v0.w*v0.w
                + v1.x*v1.x + v1.y*v1.y + v1.z*v1.z + v1.w*v1.w;
        short8v pk;
        pk[0] = (short)__bfloat16_as_ushort(__float2bfloat16(v0.x));
        pk[1] = (short)__bfloat16_as_ushort(__float2bfloat16(v0.y));
        pk[2] = (short)__bfloat16_as_ushort(__float2bfloat16(v0.z));
        pk[3] = (short)__bfloat16_as_ushort(__float2bfloat16(v0.w));
        pk[4] = (short)__bfloat16_as_ushort(__float2bfloat16(v1.x));
        pk[5] = (short)__bfloat16_as_ushort(__float2bfloat16(v1.y));
        pk[6] = (short)__bfloat16_as_ushort(__float2bfloat16(v1.z));
        pk[7] = (short)__bfloat16_as_ushort(__float2bfloat16(v1.w));
        reinterpret_cast<short8v*>(dst)[lane] = pk;
#pragma unroll
        for (int off = 32; off; off >>= 1) s += __shfl_xor(s, off, 64);
        if (lane == 0) nrm[r] = s;
    }
}

// ---- stage one operand (256 rows x 64 k) of tile kt: 4 gloads per wave -----
// Swizzle: logical (row R, 16B-chunk c of 8) lives at phys chunk c ^ (R&7).
// gload_lds writes linearly: lane -> (row R0+(lane>>3), phys lane&7), so lane
// fetches logical chunk (lane&7)^((lane>>3)&7)  (both-sides rule, rule 21).
__device__ __forceinline__ void stage_rows(
    const bf16* __restrict__ src, int rowBase, int kt, bf16* dst, int w, int lane) {
    const int k0 = kt * BK;
    const int rl = lane >> 3;                  // 0..7: row in 8-row group
    const int c  = (lane & 7) ^ rl;            // logical chunk this lane fetches
#pragma unroll
    for (int j = 0; j < 4; ++j) {
        const int R0 = w * 32 + j * 8;         // wave-uniform; 8w x 4j x 8rows = 256
        const bf16* g = src + (size_t)(rowBase + R0 + rl) * DIM + k0 + c * 8;
        __builtin_amdgcn_global_load_lds((gas1_t)g, (las3_t)(dst + R0 * BK), 16, 0, 0);
    }
}

// ---- swizzled fragment read: row-local [256][64] buf, kc = k-chunk 0..7 ----
// Lanes fr=0..15 read rows ..+fr at chunk kc^(row&7): rows 0..7 hit all 8
// chunk slots (all 32 banks), rows 8..15 repeat -> 2-way (free).
__device__ __forceinline__ bf16x8 frag(const bf16* base, int row, int kc) {
    return *reinterpret_cast<const bf16x8*>(
        base + row * BK + ((kc ^ (row & 7)) << 3));
}

#define MFMA16(A, B, C) __builtin_amdgcn_mfma_f32_16x16x32_bf16(A, B, C, 0, 0, 0)

// ---- one K-tile (K=64): stage(t+1) first, then 2x{12 ds_read + 32 MFMA} ----
// No manual lgkmcnt: compiler emits fine-grained lgkmcnt(N) between ds_read
// and MFMA (m97-verified near-optimal). One vmcnt(0)+barrier per tile.
template<bool ST, bool LAST>
__device__ __forceinline__ void ktile(
    const bf16* __restrict__ Tb, const bf16* __restrict__ Xb,
    int tBlk, int qBlk, int tS, const bf16* bufC, bf16* bufS,
    int wm, int wn, int w, int lane, f32x4 (&acc)[8][4]) {

    const bf16* cA = bufC;
    const bf16* cB = bufC + AELEMS;
    const int fr = lane & 15;
    const int fc = lane >> 4;                  // 0..3

    if (ST) {
        stage_rows(Tb, tBlk, tS, bufS, w, lane);
        stage_rows(Xb, qBlk, tS, bufS + AELEMS, w, lane);
    }
#pragma unroll
    for (int kh = 0; kh < 2; ++kh) {           // two 32-k halves, no barrier between
        const int kc = kh * 4 + fc;
        bf16x8 a[8], b[4];
#pragma unroll
        for (int m = 0; m < 8; ++m) a[m] = frag(cA, wm * 128 + m * 16 + fr, kc);
#pragma unroll
        for (int n = 0; n < 4; ++n) b[n] = frag(cB, wn * 64 + n * 16 + fr, kc);
        __builtin_amdgcn_s_setprio(1);
#pragma unroll
        for (int m = 0; m < 8; ++m)
#pragma unroll
            for (int n = 0; n < 4; ++n)
                acc[m][n] = MFMA16(a[m], b[n], acc[m][n]);
        __builtin_amdgcn_s_setprio(0);
    }
    if (!LAST) {
        asm volatile("s_waitcnt vmcnt(0)" ::: "memory");   // stage(t+1) landed
        __builtin_amdgcn_s_barrier();
        __builtin_amdgcn_sched_barrier(0);
    }
}

// ---------------- main: 256x256, 8 waves (2x4), per-wave 128x64 -------------
__global__ __launch_bounds__(512, 2) void krr_mfma_k(
    const bf16* __restrict__ Tb, const bf16* __restrict__ Xb,
    const float* __restrict__ x2, const float* __restrict__ y2,
    const float* __restrict__ coef, float* __restrict__ out) {

    __shared__ bf16 lds[2 * BUF_ELEMS];        // 128 KB: 2 bufs x (A 32K + B 32K)

    const int tid  = threadIdx.x;
    const int w    = tid >> 6;
    const int lane = tid & 63;
    const int wm   = w >> 2;                   // 0/1  (t half: 128 rows)
    const int wn   = w & 3;                    // 0..3 (q quarter: 64 rows)

    const int qBlk = blockIdx.x * BN;
    const int tBlk = blockIdx.y * BM;

    f32x4 acc[8][4];
    const f32x4 z4 = {0.f, 0.f, 0.f, 0.f};
#pragma unroll
    for (int m = 0; m < 8; ++m)
#pragma unroll
        for (int n = 0; n < 4; ++n) acc[m][n] = z4;

    // prologue: stage tile 0 -> buf0
    stage_rows(Tb, tBlk, 0, lds, w, lane);
    stage_rows(Xb, qBlk, 0, lds + AELEMS, w, lane);
    asm volatile("s_waitcnt vmcnt(0)" ::: "memory");
    __builtin_amdgcn_s_barrier();
    __builtin_amdgcn_sched_barrier(0);

#pragma unroll 1
    for (int t = 0; t < NKT - 1; ++t) {        // 7 iters: stage t+1, compute t
        const bf16* bufC = lds + (t & 1) * BUF_ELEMS;
        bf16* bufS       = lds + ((t + 1) & 1) * BUF_ELEMS;
        ktile<true, false>(Tb, Xb, tBlk, qBlk, t + 1, bufC, bufS, wm, wn, w, lane, acc);
    }
    ktile<false, true>(Tb, Xb, tBlk, qBlk, 0,
                       lds + ((NKT - 1) & 1) * BUF_ELEMS, lds, wm, wn, w, lane, acc);

    // ---- epilogue: s += exp(-(x2+y2-2*dot)) * coef, reduce over t ----------
    // C/D 16x16 (m89): col = lane&15 (q), row = (lane>>4)*4 + reg (t)
    float s[4], x2q[4];
#pragma unroll
    for (int n = 0; n < 4; ++n) {
        s[n]   = 0.f;
        x2q[n] = x2[qBlk + wn * 64 + n * 16 + (lane & 15)];
    }
#pragma unroll
    for (int m = 0; m < 8; ++m) {
        const int tb = tBlk + wm * 128 + m * 16 + ((lane >> 4) << 2);
        float y2v[4], cfv[4];
#pragma unroll
        for (int r = 0; r < 4; ++r) { y2v[r] = y2[tb + r]; cfv[r] = coef[tb + r]; }
#pragma unroll
        for (int n = 0; n < 4; ++n)
#pragma unroll
            for (int r = 0; r < 4; ++r) {
                const float d  = acc[m][n][r];
                const float sq = fmaxf(x2q[n] + y2v[r] - 2.0f * d, 0.f);
                s[n] += __expf(-sq) * cfv[r];
            }
    }
#pragma unroll
    for (int n = 0; n < 4; ++n) {
        float v = s[n];
        v += __shfl_xor(v, 16, 64);
        v += __shfl_xor(v, 32, 64);
        if (lane < 16) atomicAdd(&out[qBlk + wn * 64 + n * 16 + lane], v);
    }
}

// ---------------- fallback: plain fp32, no workspace ------------------------
__global__ void krr_naive_k(const float* __restrict__ X, const float* __restrict__ T,
                            const float* __restrict__ coef, float* __restrict__ out) {
    __shared__ float xq[DIM];
    const int q = blockIdx.x;
    for (int i = threadIdx.x; i < DIM; i += 256) xq[i] = X[(size_t)q * DIM + i];
    __syncthreads();
    float s2 = 0.f;
    for (int i = 0; i < DIM; ++i) s2 += xq[i] * xq[i];
    float acc = 0.f;
    for (int t = threadIdx.x; t < NT; t += 256) {
        const float* ty = T + (size_t)t * DIM;
        float dot = 0.f, yy = 0.f;
        for (int i = 0; i < DIM; ++i) { float yv = ty[i]; dot += xq[i] * yv; yy += yv * yv; }
        float sq = fmaxf(s2 + yy - 2.0f * dot, 0.f);
        acc += __expf(-sq) * coef[t];
    }
#pragma unroll
    for (int off = 32; off > 0; off >>= 1) acc += __shfl_down(acc, off, 64);
    __shared__ float red[4];
    if ((threadIdx.x & 63) == 0) red[threadIdx.x >> 6] = acc;
    __syncthreads();
    if (threadIdx.x == 0) out[q] = red[0] + red[1] + red[2] + red[3];
}

extern "C" void kernel_launch(void* const* d_in, const int* in_sizes, int n_in,
                              void* d_out, int out_size, void* d_ws, size_t ws_size,
                              hipStream_t stream) {
    const float* X    = (const float*)d_in[0];
    const float* T    = (const float*)d_in[1];
    const float* coef = (const float*)d_in[2];
    float* out = (float*)d_out;

    zero_out_k<<<NQ / 256, 256, 0, stream>>>(out);

    const size_t need = (size_t)(NQ + NT) * DIM * sizeof(bf16) + (size_t)(NQ + NT) * sizeof(float);
    if (ws_size >= need) {
        bf16* Xb  = (bf16*)d_ws;
        bf16* Tb  = Xb + (size_t)NQ * DIM;
        float* x2 = (float*)(Tb + (size_t)NT * DIM);
        float* y2 = x2 + NQ;
        prep_k<<<2048, 256, 0, stream>>>(X, T, Xb, Tb, x2, y2);
        dim3 grid(NQ / BN, NT / BM);
        krr_mfma_k<<<grid, 512, 0, stream>>>(Tb, Xb, x2, y2, coef, out);
    } else {
        krr_naive_k<<<NQ, 256, 0, stream>>>(X, T, coef, out);
    }
}

// Round 14
// 145.889 us; speedup vs baseline: 1.1311x; 1.0045x over previous
//
#include <hip/hip_runtime.h>
#include <hip/hip_bf16.h>
#include <stdint.h>

#define NQ 8192
#define NT 8192
#define DIM 512                 // elements per row; fp8 row = 512 B
#define BKB 128                 // K-tile = 128 fp8 elements (128 B)
#define NKT (DIM / BKB)         // 4 K-tiles
#define BM 256
#define BN 256
#define ABYTES (BM * BKB)       // 32 KB per operand tile
#define BUFB ((BM + BN) * BKB)  // 64 KB per buffer

using f32x4  = __attribute__((ext_vector_type(4))) float;
using i32x4  = __attribute__((ext_vector_type(4))) int;
using i32x8  = __attribute__((ext_vector_type(8))) int;

typedef __attribute__((address_space(1))) void* gas1_t;
typedef __attribute__((address_space(3))) void* las3_t;

// ---------------- zero the output (harness poisons with 0xAA) ---------------
__global__ void zero_out_k(float* __restrict__ out) {
    out[blockIdx.x * 256 + threadIdx.x] = 0.0f;
}

// ---------------- prepass: fp32 -> fp8 e4m3 + fp32 row norms ----------------
// 2048 blocks x 256 thr; wave handles 2 rows; 8 elems/lane.
__global__ void prep_k(const float* __restrict__ X, const float* __restrict__ T,
                       uint8_t* __restrict__ Xb, uint8_t* __restrict__ Tb,
                       float* __restrict__ x2, float* __restrict__ y2) {
    const int w    = threadIdx.x >> 6;
    const int lane = threadIdx.x & 63;
    const int wid  = blockIdx.x * 4 + w;
#pragma unroll
    for (int rr = 0; rr < 2; ++rr) {
        const int row = wid * 2 + rr;
        const float* src; uint8_t* dst; float* nrm; int r;
        if (row < NQ) { r = row;      src = X + (size_t)r * DIM; dst = Xb + (size_t)r * DIM; nrm = x2; }
        else          { r = row - NQ; src = T + (size_t)r * DIM; dst = Tb + (size_t)r * DIM; nrm = y2; }
        const float4 v0 = reinterpret_cast<const float4*>(src)[lane * 2];
        const float4 v1 = reinterpret_cast<const float4*>(src)[lane * 2 + 1];
        float s = v0.x*v0.x + v0.y*v0.y + v0.z*v0.z + v0.w*v0.w
                + v1.x*v1.x + v1.y*v1.y + v1.z*v1.z + v1.w*v1.w;
        int lo = __builtin_amdgcn_cvt_pk_fp8_f32(v0.x, v0.y, 0, false);
        lo     = __builtin_amdgcn_cvt_pk_fp8_f32(v0.z, v0.w, lo, true);
        int hi = __builtin_amdgcn_cvt_pk_fp8_f32(v1.x, v1.y, 0, false);
        hi     = __builtin_amdgcn_cvt_pk_fp8_f32(v1.z, v1.w, hi, true);
        reinterpret_cast<int2*>(dst)[lane] = make_int2(lo, hi);
#pragma unroll
        for (int off = 32; off; off >>= 1) s += __shfl_xor(s, off, 64);
        if (lane == 0) nrm[r] = s;
    }
}

// ---- stage one operand (256 rows x 128 B) of tile kt: 4 gloads per wave ----
// Swizzle: logical (row R, 16B-chunk c of 8) at phys chunk c ^ (R&7).
// gload_lds writes linearly: lane -> (row R0+(lane>>3), phys chunk lane&7), so
// the lane fetches logical chunk (lane&7)^((lane>>3)&7) (both-sides, rule 21).
__device__ __forceinline__ void stage_rows(
    const uint8_t* __restrict__ src, int rowBase, int kt, uint8_t* dst, int w, int lane) {
    const int k0 = kt * BKB;
    const int rl = lane >> 3;                  // 0..7: row in 8-row group
    const int c  = (lane & 7) ^ rl;            // logical chunk this lane fetches
#pragma unroll
    for (int j = 0; j < 4; ++j) {
        const int R0 = w * 32 + j * 8;         // wave-uniform; 8w x 4j x 8rows = 256
        const uint8_t* g = src + (size_t)(rowBase + R0 + rl) * DIM + k0 + c * 16;
        __builtin_amdgcn_global_load_lds((gas1_t)g, (las3_t)(dst + R0 * BKB), 16, 0, 0);
    }
}

// ---- swizzled fragment read: lane (fr,fc) reads row base+fr, k-bytes fc*32 --
// Two b128 reads at phys chunks (2fc)^(row&7), (2fc+1)^(row&7): 8 lanes per
// 16B chunk-column, uniformly spread -> 2-way on banks (free, r13-verified 0).
__device__ __forceinline__ i32x8 frag8(const uint8_t* base, int row, int fc) {
    const uint8_t* p = base + row * BKB;
    const i32x4 lo = *reinterpret_cast<const i32x4*>(p + ((( 2 * fc )     ^ (row & 7)) << 4));
    const i32x4 hi = *reinterpret_cast<const i32x4*>(p + (((2 * fc + 1) ^ (row & 7)) << 4));
    i32x8 r = { lo[0], lo[1], lo[2], lo[3], hi[0], hi[1], hi[2], hi[3] };
    return r;
}

// MX-scaled fp8 MFMA, uniform scale = 2^0 (E8M0 127) -> plain fp8 GEMM at 2x rate
#define MFMA_FP8(A, B, C)                                               \
    __builtin_amdgcn_mfma_scale_f32_16x16x128_f8f6f4(                   \
        (A), (B), (C), 0 /*cbsz: fp8*/, 0 /*blgp: fp8*/,                \
        0, 0x7F7F7F7F, 0, 0x7F7F7F7F)

// ---- one K-tile (K=128): stage(t+1) first, then 24 ds_read + 32 MFMA -------
// Compiler emits fine-grained lgkmcnt between ds_read and MFMA (m97-verified).
// One vmcnt(0)+barrier per tile; 4 barriers total.
template<bool ST, bool LAST>
__device__ __forceinline__ void ktile(
    const uint8_t* __restrict__ Tb, const uint8_t* __restrict__ Xb,
    int tBlk, int qBlk, int tS, const uint8_t* bufC, uint8_t* bufS,
    int wm, int wn, int w, int lane, f32x4 (&acc)[8][4]) {

    const uint8_t* cA = bufC;
    const uint8_t* cB = bufC + ABYTES;
    const int fr = lane & 15;
    const int fc = lane >> 4;                  // 0..3: 32-byte k-group

    if (ST) {
        stage_rows(Tb, tBlk, tS, bufS, w, lane);
        stage_rows(Xb, qBlk, tS, bufS + ABYTES, w, lane);
    }
    i32x8 a[8], b[4];
#pragma unroll
    for (int m = 0; m < 8; ++m) a[m] = frag8(cA, wm * 128 + m * 16 + fr, fc);
#pragma unroll
    for (int n = 0; n < 4; ++n) b[n] = frag8(cB, wn * 64 + n * 16 + fr, fc);
    __builtin_amdgcn_s_setprio(1);
#pragma unroll
    for (int m = 0; m < 8; ++m)
#pragma unroll
        for (int n = 0; n < 4; ++n)
            acc[m][n] = MFMA_FP8(a[m], b[n], acc[m][n]);
    __builtin_amdgcn_s_setprio(0);
    if (!LAST) {
        asm volatile("s_waitcnt vmcnt(0)" ::: "memory");   // stage(t+1) landed
        __builtin_amdgcn_s_barrier();
        __builtin_amdgcn_sched_barrier(0);
    }
}

// ---------------- main: 256x256, 8 waves (2x4), per-wave 128x64 -------------
__global__ __launch_bounds__(512, 2) void krr_mfma_k(
    const uint8_t* __restrict__ Tb, const uint8_t* __restrict__ Xb,
    const float* __restrict__ x2, const float* __restrict__ y2,
    const float* __restrict__ coef, float* __restrict__ out) {

    __shared__ uint8_t lds[2 * BUFB];          // 128 KB: 2 bufs x (A 32K + B 32K)

    const int tid  = threadIdx.x;
    const int w    = tid >> 6;
    const int lane = tid & 63;
    const int wm   = w >> 2;                   // 0/1  (t half: 128 rows)
    const int wn   = w & 3;                    // 0..3 (q quarter: 64 rows)

    const int qBlk = blockIdx.x * BN;
    const int tBlk = blockIdx.y * BM;

    f32x4 acc[8][4];
    const f32x4 z4 = {0.f, 0.f, 0.f, 0.f};
#pragma unroll
    for (int m = 0; m < 8; ++m)
#pragma unroll
        for (int n = 0; n < 4; ++n) acc[m][n] = z4;

    // prologue: stage tile 0 -> buf0
    stage_rows(Tb, tBlk, 0, lds, w, lane);
    stage_rows(Xb, qBlk, 0, lds + ABYTES, w, lane);
    asm volatile("s_waitcnt vmcnt(0)" ::: "memory");
    __builtin_amdgcn_s_barrier();
    __builtin_amdgcn_sched_barrier(0);

#pragma unroll 1
    for (int t = 0; t < NKT - 1; ++t) {        // 3 iters: stage t+1, compute t
        const uint8_t* bufC = lds + (t & 1) * BUFB;
        uint8_t* bufS       = lds + ((t + 1) & 1) * BUFB;
        ktile<true, false>(Tb, Xb, tBlk, qBlk, t + 1, bufC, bufS, wm, wn, w, lane, acc);
    }
    ktile<false, true>(Tb, Xb, tBlk, qBlk, 0,
                       lds + ((NKT - 1) & 1) * BUFB, lds, wm, wn, w, lane, acc);

    // ---- epilogue: s += exp(-(x2+y2-2*dot)) * coef, reduce over t ----------
    // C/D 16x16 (m89, dtype-independent): col = lane&15 (q), row = (lane>>4)*4 + reg (t)
    float s[4], x2q[4];
#pragma unroll
    for (int n = 0; n < 4; ++n) {
        s[n]   = 0.f;
        x2q[n] = x2[qBlk + wn * 64 + n * 16 + (lane & 15)];
    }
#pragma unroll
    for (int m = 0; m < 8; ++m) {
        const int tb = tBlk + wm * 128 + m * 16 + ((lane >> 4) << 2);
        float y2v[4], cfv[4];
#pragma unroll
        for (int r = 0; r < 4; ++r) { y2v[r] = y2[tb + r]; cfv[r] = coef[tb + r]; }
#pragma unroll
        for (int n = 0; n < 4; ++n)
#pragma unroll
            for (int r = 0; r < 4; ++r) {
                const float d  = acc[m][n][r];
                const float sq = fmaxf(x2q[n] + y2v[r] - 2.0f * d, 0.f);
                s[n] += __expf(-sq) * cfv[r];
            }
    }
#pragma unroll
    for (int n = 0; n < 4; ++n) {
        float v = s[n];
        v += __shfl_xor(v, 16, 64);
        v += __shfl_xor(v, 32, 64);
        if (lane < 16) atomicAdd(&out[qBlk + wn * 64 + n * 16 + lane], v);
    }
}

// ---------------- fallback: plain fp32, no workspace ------------------------
__global__ void krr_naive_k(const float* __restrict__ X, const float* __restrict__ T,
                            const float* __restrict__ coef, float* __restrict__ out) {
    __shared__ float xq[DIM];
    const int q = blockIdx.x;
    for (int i = threadIdx.x; i < DIM; i += 256) xq[i] = X[(size_t)q * DIM + i];
    __syncthreads();
    float s2 = 0.f;
    for (int i = 0; i < DIM; ++i) s2 += xq[i] * xq[i];
    float acc = 0.f;
    for (int t = threadIdx.x; t < NT; t += 256) {
        const float* ty = T + (size_t)t * DIM;
        float dot = 0.f, yy = 0.f;
        for (int i = 0; i < DIM; ++i) { float yv = ty[i]; dot += xq[i] * yv; yy += yv * yv; }
        float sq = fmaxf(s2 + yy - 2.0f * dot, 0.f);
        acc += __expf(-sq) * coef[t];
    }
#pragma unroll
    for (int off = 32; off > 0; off >>= 1) acc += __shfl_down(acc, off, 64);
    __shared__ float red[4];
    if ((threadIdx.x & 63) == 0) red[threadIdx.x >> 6] = acc;
    __syncthreads();
    if (threadIdx.x == 0) out[q] = red[0] + red[1] + red[2] + red[3];
}

extern "C" void kernel_launch(void* const* d_in, const int* in_sizes, int n_in,
                              void* d_out, int out_size, void* d_ws, size_t ws_size,
                              hipStream_t stream) {
    const float* X    = (const float*)d_in[0];
    const float* T    = (const float*)d_in[1];
    const float* coef = (const float*)d_in[2];
    float* out = (float*)d_out;

    zero_out_k<<<NQ / 256, 256, 0, stream>>>(out);

    const size_t need = (size_t)(NQ + NT) * DIM + (size_t)(NQ + NT) * sizeof(float);
    if (ws_size >= need) {
        uint8_t* Xb = (uint8_t*)d_ws;
        uint8_t* Tb = Xb + (size_t)NQ * DIM;
        float* x2   = (float*)(Tb + (size_t)NT * DIM);
        float* y2   = x2 + NQ;
        prep_k<<<2048, 256, 0, stream>>>(X, T, Xb, Tb, x2, y2);
        dim3 grid(NQ / BN, NT / BM);
        krr_mfma_k<<<grid, 512, 0, stream>>>(Tb, Xb, x2, y2, coef, out);
    } else {
        krr_naive_k<<<NQ, 256, 0, stream>>>(X, T, coef, out);
    }
}

// Round 16
// 123.436 us; speedup vs baseline: 1.3368x; 1.1819x over previous
//
#include <hip/hip_runtime.h>
#include <hip/hip_bf16.h>
#include <stdint.h>

#define NQ 8192
#define NT 8192
#define DIM 512                 // elements per row; fp8 row = 512 B
#define BKB 128                 // K-tile = 128 fp8 elements (128 B staged)
#define NKT (DIM / BKB)         // 4 K-tiles
#define BM 256
#define BN 256
#define ABYTES (BM * BKB)       // 32 KB per operand tile
#define BUFB ((BM + BN) * BKB)  // 64 KB per buffer

using f32x16 = __attribute__((ext_vector_type(16))) float;
using i32x4  = __attribute__((ext_vector_type(4))) int;
using i32x8  = __attribute__((ext_vector_type(8))) int;

typedef __attribute__((address_space(1))) void* gas1_t;
typedef __attribute__((address_space(3))) void* las3_t;

// ---------------- zero the output (harness poisons with 0xAA) ---------------
__global__ void zero_out_k(float* __restrict__ out) {
    out[blockIdx.x * 256 + threadIdx.x] = 0.0f;
}

// ---------------- prepass: fp32 -> fp8 e4m3 + fp32 row norms ----------------
__global__ void prep_k(const float* __restrict__ X, const float* __restrict__ T,
                       uint8_t* __restrict__ Xb, uint8_t* __restrict__ Tb,
                       float* __restrict__ x2, float* __restrict__ y2) {
    const int w    = threadIdx.x >> 6;
    const int lane = threadIdx.x & 63;
    const int wid  = blockIdx.x * 4 + w;
#pragma unroll
    for (int rr = 0; rr < 2; ++rr) {
        const int row = wid * 2 + rr;
        const float* src; uint8_t* dst; float* nrm; int r;
        if (row < NQ) { r = row;      src = X + (size_t)r * DIM; dst = Xb + (size_t)r * DIM; nrm = x2; }
        else          { r = row - NQ; src = T + (size_t)r * DIM; dst = Tb + (size_t)r * DIM; nrm = y2; }
        const float4 v0 = reinterpret_cast<const float4*>(src)[lane * 2];
        const float4 v1 = reinterpret_cast<const float4*>(src)[lane * 2 + 1];
        float s = v0.x*v0.x + v0.y*v0.y + v0.z*v0.z + v0.w*v0.w
                + v1.x*v1.x + v1.y*v1.y + v1.z*v1.z + v1.w*v1.w;
        int lo = __builtin_amdgcn_cvt_pk_fp8_f32(v0.x, v0.y, 0, false);
        lo     = __builtin_amdgcn_cvt_pk_fp8_f32(v0.z, v0.w, lo, true);
        int hi = __builtin_amdgcn_cvt_pk_fp8_f32(v1.x, v1.y, 0, false);
        hi     = __builtin_amdgcn_cvt_pk_fp8_f32(v1.z, v1.w, hi, true);
        reinterpret_cast<int2*>(dst)[lane] = make_int2(lo, hi);
#pragma unroll
        for (int off = 32; off; off >>= 1) s += __shfl_xor(s, off, 64);
        if (lane == 0) nrm[r] = s;
    }
}

// ---- stage one operand (256 rows x 128 B) of tile kt: 4 gloads per wave ----
// Identical to r13's measured-0-conflict pattern. Swizzle: logical (row R,
// 16B-chunk c of 8) at phys chunk c ^ (R&7); per-lane pre-swizzled global src.
__device__ __forceinline__ void stage_rows(
    const uint8_t* __restrict__ src, int rowBase, int kt, uint8_t* dst, int w, int lane) {
    const int k0 = kt * BKB;
    const int rl = lane >> 3;                  // 0..7: row in 8-row group
    const int c  = (lane & 7) ^ rl;            // logical chunk this lane fetches
#pragma unroll
    for (int j = 0; j < 4; ++j) {
        const int R0 = w * 32 + j * 8;         // wave-uniform; 8w x 4j x 8rows = 256
        const uint8_t* g = src + (size_t)(rowBase + R0 + rl) * DIM + k0 + c * 16;
        __builtin_amdgcn_global_load_lds((gas1_t)g, (las3_t)(dst + R0 * BKB), 16, 0, 0);
    }
}

// ---- fragment read for 32x32x64: lane holds 32 B = logical chunks L1, L1^4 --
// Phys = logical ^ (row&7). k-permutation across (kg,kh) is IDENTICAL for A
// and B, so the MFMA contraction is invariant to the chunk ordering.
__device__ __forceinline__ i32x8 frag32(const uint8_t* base, int row, int L1) {
    const uint8_t* p = base + row * BKB;
    const i32x4 lo = *reinterpret_cast<const i32x4*>(p + ((( L1      ^ (row & 7))) << 4));
    const i32x4 hi = *reinterpret_cast<const i32x4*>(p + ((((L1 ^ 4) ^ (row & 7))) << 4));
    i32x8 r = { lo[0], lo[1], lo[2], lo[3], hi[0], hi[1], hi[2], hi[3] };
    return r;
}

// MX-scaled fp8 MFMA, uniform scale 2^0 (E8M0 127) -> plain fp8 GEMM at 2x rate
#define MFMA32_FP8(A, B, C)                                             \
    __builtin_amdgcn_mfma_scale_f32_32x32x64_f8f6f4(                    \
        (A), (B), (C), 0 /*cbsz: fp8*/, 0 /*blgp: fp8*/,                \
        0, 0x7F7F7F7F, 0, 0x7F7F7F7F)

// ---- one K-tile (128 B staged = 2 x K=64 MFMA halves) ----------------------
// Per half: 2 B-frags + stream 4 A-frags -> 8 MFMAs; sched_barrier between
// halves caps the live-register window (anti-spill). One vmcnt(0)+barrier/tile.
template<bool ST, bool LAST>
__device__ __forceinline__ void ktile(
    const uint8_t* __restrict__ Tb, const uint8_t* __restrict__ Xb,
    int tBlk, int qBlk, int tS, const uint8_t* bufC, uint8_t* bufS,
    int wm, int wn, int w, int lane, f32x16 (&acc)[4][2]) {

    const uint8_t* cA = bufC;
    const uint8_t* cB = bufC + ABYTES;
    const int l31 = lane & 31;
    const int kg  = lane >> 5;                 // 0/1

    if (ST) {
        stage_rows(Tb, tBlk, tS, bufS, w, lane);
        stage_rows(Xb, qBlk, tS, bufS + ABYTES, w, lane);
    }
#pragma unroll
    for (int kh = 0; kh < 2; ++kh) {
        const int L1 = kh * 2 + kg;            // logical chunk pair {L1, L1^4}
        i32x8 b[2];
#pragma unroll
        for (int ni = 0; ni < 2; ++ni)
            b[ni] = frag32(cB, wn * 64 + ni * 32 + l31, L1);
        __builtin_amdgcn_s_setprio(1);
#pragma unroll
        for (int mi = 0; mi < 4; ++mi) {
            const i32x8 a = frag32(cA, wm * 128 + mi * 32 + l31, L1);
            acc[mi][0] = MFMA32_FP8(a, b[0], acc[mi][0]);
            acc[mi][1] = MFMA32_FP8(a, b[1], acc[mi][1]);
        }
        __builtin_amdgcn_s_setprio(0);
        __builtin_amdgcn_sched_barrier(0);     // cap live window per half
    }
    if (!LAST) {
        asm volatile("s_waitcnt vmcnt(0)" ::: "memory");   // stage(t+1) landed
        __builtin_amdgcn_s_barrier();
        __builtin_amdgcn_sched_barrier(0);
    }
}

// ---------------- main: 256x256, 8 waves (2x4), per-wave 128x64 -------------
__global__ __launch_bounds__(512, 2) void krr_mfma_k(
    const uint8_t* __restrict__ Tb, const uint8_t* __restrict__ Xb,
    const float* __restrict__ x2, const float* __restrict__ y2,
    const float* __restrict__ coef, float* __restrict__ out) {

    __shared__ uint8_t lds[2 * BUFB];          // 128 KB

    const int tid  = threadIdx.x;
    const int w    = tid >> 6;
    const int lane = tid & 63;
    const int wm   = w >> 2;                   // 0/1  (t half: 128 rows)
    const int wn   = w & 3;                    // 0..3 (q quarter: 64 rows)

    const int qBlk = blockIdx.x * BN;
    const int tBlk = blockIdx.y * BM;

    f32x16 acc[4][2];
#pragma unroll
    for (int mi = 0; mi < 4; ++mi)
#pragma unroll
        for (int ni = 0; ni < 2; ++ni)
#pragma unroll
            for (int r = 0; r < 16; ++r) acc[mi][ni][r] = 0.f;

    // prologue: stage tile 0 -> buf0
    stage_rows(Tb, tBlk, 0, lds, w, lane);
    stage_rows(Xb, qBlk, 0, lds + ABYTES, w, lane);
    asm volatile("s_waitcnt vmcnt(0)" ::: "memory");
    __builtin_amdgcn_s_barrier();
    __builtin_amdgcn_sched_barrier(0);

#pragma unroll 1
    for (int t = 0; t < NKT - 1; ++t) {        // 3 iters: stage t+1, compute t
        const uint8_t* bufC = lds + (t & 1) * BUFB;
        uint8_t* bufS       = lds + ((t + 1) & 1) * BUFB;
        ktile<true, false>(Tb, Xb, tBlk, qBlk, t + 1, bufC, bufS, wm, wn, w, lane, acc);
    }
    ktile<false, true>(Tb, Xb, tBlk, qBlk, 0,
                       lds + ((NKT - 1) & 1) * BUFB, lds, wm, wn, w, lane, acc);

    // ---- epilogue: s += exp(-(x2+y2-2*dot)) * coef, reduce over t ----------
    // C/D 32x32 (m74/m101): col = lane&31 (q), row = (r&3)+8*(r>>2)+4*(lane>>5) (t)
    const int l31 = lane & 31;
    float s[2], x2q[2];
#pragma unroll
    for (int ni = 0; ni < 2; ++ni) {
        s[ni]   = 0.f;
        x2q[ni] = x2[qBlk + wn * 64 + ni * 32 + l31];
    }
#pragma unroll
    for (int mi = 0; mi < 4; ++mi) {
        const int tb = tBlk + wm * 128 + mi * 32 + 4 * (lane >> 5);
        float y2v[16], cfv[16];
#pragma unroll
        for (int r = 0; r < 16; ++r) {
            const int t = tb + (r & 3) + 8 * (r >> 2);
            y2v[r] = y2[t];
            cfv[r] = coef[t];
        }
#pragma unroll
        for (int ni = 0; ni < 2; ++ni)
#pragma unroll
            for (int r = 0; r < 16; ++r) {
                const float d  = acc[mi][ni][r];
                const float sq = fmaxf(x2q[ni] + y2v[r] - 2.0f * d, 0.f);
                s[ni] += __expf(-sq) * cfv[r];
            }
    }
#pragma unroll
    for (int ni = 0; ni < 2; ++ni) {
        s[ni] += __shfl_xor(s[ni], 32, 64);
        if (lane < 32) atomicAdd(&out[qBlk + wn * 64 + ni * 32 + l31], s[ni]);
    }
}

// ---------------- fallback: plain fp32, no workspace ------------------------
__global__ void krr_naive_k(const float* __restrict__ X, const float* __restrict__ T,
                            const float* __restrict__ coef, float* __restrict__ out) {
    __shared__ float xq[DIM];
    const int q = blockIdx.x;
    for (int i = threadIdx.x; i < DIM; i += 256) xq[i] = X[(size_t)q * DIM + i];
    __syncthreads();
    float s2 = 0.f;
    for (int i = 0; i < DIM; ++i) s2 += xq[i] * xq[i];
    float acc = 0.f;
    for (int t = threadIdx.x; t < NT; t += 256) {
        const float* ty = T + (size_t)t * DIM;
        float dot = 0.f, yy = 0.f;
        for (int i = 0; i < DIM; ++i) { float yv = ty[i]; dot += xq[i] * yv; yy += yv * yv; }
        float sq = fmaxf(s2 + yy - 2.0f * dot, 0.f);
        acc += __expf(-sq) * coef[t];
    }
#pragma unroll
    for (int off = 32; off > 0; off >>= 1) acc += __shfl_down(acc, off, 64);
    __shared__ float red[4];
    if ((threadIdx.x & 63) == 0) red[threadIdx.x >> 6] = acc;
    __syncthreads();
    if (threadIdx.x == 0) out[q] = red[0] + red[1] + red[2] + red[3];
}

extern "C" void kernel_launch(void* const* d_in, const int* in_sizes, int n_in,
                              void* d_out, int out_size, void* d_ws, size_t ws_size,
                              hipStream_t stream) {
    const float* X    = (const float*)d_in[0];
    const float* T    = (const float*)d_in[1];
    const float* coef = (const float*)d_in[2];
    float* out = (float*)d_out;

    zero_out_k<<<NQ / 256, 256, 0, stream>>>(out);

    const size_t need = (size_t)(NQ + NT) * DIM + (size_t)(NQ + NT) * sizeof(float);
    if (ws_size >= need) {
        uint8_t* Xb = (uint8_t*)d_ws;
        uint8_t* Tb = Xb + (size_t)NQ * DIM;
        float* x2   = (float*)(Tb + (size_t)NT * DIM);
        float* y2   = x2 + NQ;
        prep_k<<<2048, 256, 0, stream>>>(X, T, Xb, Tb, x2, y2);
        dim3 grid(NQ / BN, NT / BM);
        krr_mfma_k<<<grid, 512, 0, stream>>>(Tb, Xb, x2, y2, coef, out);
    } else {
        krr_naive_k<<<NQ, 256, 0, stream>>>(X, T, coef, out);
    }
}